// Round 2
// baseline (237.216 us; speedup 1.0000x reference)
//
#include <hip/hip_runtime.h>
#include <hip/hip_bf16.h>
#include <stdint.h>

#define NN 2048
#define BK 32
#define NK (NN / BK)   // 64 K-tiles

typedef __bf16 bf16;
typedef __bf16 bf16x8 __attribute__((ext_vector_type(8)));
typedef __bf16 bf16x4 __attribute__((ext_vector_type(4)));
typedef float f32x4 __attribute__((ext_vector_type(4)));

// async global->LDS, 16B per lane (LDS dest = wave-uniform base + lane*16)
__device__ __forceinline__ void async_copy16(bf16* lds, const bf16* g) {
    __builtin_amdgcn_global_load_lds(
        (const __attribute__((address_space(1))) unsigned int*)g,
        (__attribute__((address_space(3))) unsigned int*)lds,
        16, 0, 0);
}

#define WAIT_VM(n) asm volatile("s_waitcnt vmcnt(" #n ")" ::: "memory")
#define LGKM0()    asm volatile("s_waitcnt lgkmcnt(0)" ::: "memory")
#define BAR()                                  \
    do {                                       \
        asm volatile("" ::: "memory");         \
        __builtin_amdgcn_s_barrier();          \
        asm volatile("" ::: "memory");         \
    } while (0)

// ---------------------------------------------------------------------------
// fp32 -> bf16 transpose cast, z-batched. 64x64 tile, 256 threads. (unchanged)
// ---------------------------------------------------------------------------
struct CastArgs {
    const float* in[4];
    bf16*        outT[4];
    bf16*        outN[4];
};

__global__ __launch_bounds__(256) void transpose_cast_kernel(CastArgs args) {
    const float* __restrict__ in = args.in[blockIdx.z];
    bf16* __restrict__ outT      = args.outT[blockIdx.z];
    bf16* __restrict__ outN      = args.outN[blockIdx.z];
    __shared__ float tile[64][65];
    const int bx = blockIdx.x * 64;   // col base
    const int by = blockIdx.y * 64;   // row base
    const int t  = threadIdx.x;
    const int c4 = (t & 15) * 4, r0 = t >> 4;
#pragma unroll
    for (int p = 0; p < 4; ++p) {
        const int r = r0 + p * 16;
        const float4 v = *(const float4*)&in[(size_t)(by + r) * NN + bx + c4];
        tile[r][c4 + 0] = v.x; tile[r][c4 + 1] = v.y;
        tile[r][c4 + 2] = v.z; tile[r][c4 + 3] = v.w;
        if (outN) {
            bf16x4 b = {(bf16)v.x, (bf16)v.y, (bf16)v.z, (bf16)v.w};
            *(bf16x4*)&outN[(size_t)(by + r) * NN + bx + c4] = b;
        }
    }
    __syncthreads();
    const int cc8 = (t & 7) * 8, rw0 = t >> 3;
#pragma unroll
    for (int p = 0; p < 2; ++p) {
        const int rw = rw0 + p * 32;
        bf16x8 b;
#pragma unroll
        for (int i = 0; i < 8; ++i) b[i] = (bf16)tile[cc8 + i][rw];
        *(bf16x8*)&outT[(size_t)(bx + rw) * NN + by + cc8] = b;
    }
}

// ---------------------------------------------------------------------------
// Phased 8-wave GEMM core, 128x128 tile, BK=32, depth-4 buffering (96 KiB).
// Per K-tile: {ds_read frags | issue tile kt+3 prefetch} -> BAR -> lgkmcnt(0)
//   -> setprio(1) -> 16 MFMA -> setprio(0) -> counted vmcnt -> BAR.
// z=0: dual-B (M1 = A@W1, M2 = A@W2 share A) + fused M1bf/B1bf emission.
// z=1: single (M3 = W3@W3).
// ---------------------------------------------------------------------------
struct P1Args {
    const bf16*  Abf;
    const bf16*  W1t;
    const bf16*  W2t;
    const bf16*  W3bf;
    const bf16*  W3t;
    float*       M1;
    float*       M2out;
    float*       M3;
    const float* W1;
    bf16*        M1bf;
    bf16*        B1bf;
};

__global__ __launch_bounds__(512, 2) void gemm_dual_kernel(P1Args a) {
    __shared__ __align__(16) bf16 LA[4][128 * BK];
    __shared__ __align__(16) bf16 LB[4][128 * BK];
    __shared__ __align__(16) bf16 LC[4][128 * BK];

    const int t = threadIdx.x;
    // bijective XCD swizzle (256 wg, 256 % 8 == 0): each XCD gets 2 bm-rows
    const int wg  = blockIdx.y * 16 + blockIdx.x;
    const int swz = (wg & 7) * 32 + (wg >> 3);
    const int bm  = (swz >> 4) * 128;
    const int bn  = (swz & 15) * 128;

    // staging map: thread t -> (row = t>>2, chunk = t&3), XOR-swizzled source
    const int srow = t >> 2;
    const int sch  = t & 3;
    const int scol = ((sch ^ ((srow >> 1) & 3)) << 3);
    const int off0 = t * 8;

    const int wave = t >> 6;
    const int lane = t & 63;
    const int lrow = lane & 15;
    const int q    = lane >> 4;
    const int qe   = (q ^ ((lrow >> 1) & 3)) << 3;  // XOR-swizzled read chunk

    if (blockIdx.z == 0) {
        // ---- dual-B: acc1 = A@W1 tile, acc2 = A@W2 tile, shared A frags ----
        const int wm = (wave >> 2) * 64;   // 2 waves along M
        const int wn = (wave & 3) * 32;    // 4 waves along N (max B reuse)

        const bf16* gA  = a.Abf + (size_t)(bm + srow) * NN + scol;
        const bf16* gB1 = a.W1t + (size_t)(bn + srow) * NN + scol;
        const bf16* gB2 = a.W2t + (size_t)(bn + srow) * NN + scol;

        f32x4 acc1[4][2], acc2[4][2];
#pragma unroll
        for (int i = 0; i < 4; ++i)
#pragma unroll
            for (int j = 0; j < 2; ++j) {
                acc1[i][j] = (f32x4){0.f, 0.f, 0.f, 0.f};
                acc2[i][j] = (f32x4){0.f, 0.f, 0.f, 0.f};
            }

        auto issue = [&](int buf, int kt) {
            const int kof = kt * BK;
            async_copy16(&LA[buf][off0], gA  + kof);
            async_copy16(&LB[buf][off0], gB1 + kof);
            async_copy16(&LC[buf][off0], gB2 + kof);
        };

        issue(0, 0); issue(1, 1); issue(2, 2);   // 9 outstanding
        WAIT_VM(6); BAR();                        // tile 0 landed

#pragma unroll 1
        for (int kt = 0; kt < NK; ++kt) {
            const int b = kt & 3;
            const bf16* cA = LA[b];
            const bf16* cB = LB[b];
            const bf16* cC = LC[b];

            bf16x8 af[4], f1[2], f2[2];
#pragma unroll
            for (int i = 0; i < 4; ++i)
                af[i] = *(const bf16x8*)&cA[(wm + i * 16 + lrow) * BK + qe];
#pragma unroll
            for (int j = 0; j < 2; ++j) {
                f1[j] = *(const bf16x8*)&cB[(wn + j * 16 + lrow) * BK + qe];
                f2[j] = *(const bf16x8*)&cC[(wn + j * 16 + lrow) * BK + qe];
            }
            if (kt < NK - 3) issue((kt + 3) & 3, kt + 3);

            BAR(); LGKM0();
            __builtin_amdgcn_s_setprio(1);
#pragma unroll
            for (int i = 0; i < 4; ++i)
#pragma unroll
                for (int j = 0; j < 2; ++j) {
                    acc1[i][j] = __builtin_amdgcn_mfma_f32_16x16x32_bf16(
                        af[i], f1[j], acc1[i][j], 0, 0, 0);
                    acc2[i][j] = __builtin_amdgcn_mfma_f32_16x16x32_bf16(
                        af[i], f2[j], acc2[i][j], 0, 0, 0);
                }
            __builtin_amdgcn_s_setprio(0);
            // counted drain: tile kt+1 complete, kt+2/kt+3 stay in flight
            if (kt < NK - 3)       { WAIT_VM(6); }
            else if (kt == NK - 3) { WAIT_VM(3); }
            else                   { WAIT_VM(0); }
            BAR();
        }

        // epilogue: M1, M2(out), M1bf, B1bf = bf16(M1*W1)
#pragma unroll
        for (int i = 0; i < 4; ++i)
#pragma unroll
            for (int j = 0; j < 2; ++j)
#pragma unroll
                for (int r = 0; r < 4; ++r) {
                    const size_t idx =
                        (size_t)(bm + wm + i * 16 + q * 4 + r) * NN +
                        (bn + wn + j * 16 + lrow);
                    const float v1 = acc1[i][j][r];
                    a.M1[idx]    = v1;
                    a.M2out[idx] = acc2[i][j][r];
                    const float w = a.W1[idx];
                    a.M1bf[idx] = (bf16)v1;
                    a.B1bf[idx] = (bf16)(v1 * w);
                }
    } else {
        // ---- single: M3 = W3 @ W3 ----
        const int wm = (wave >> 2) * 64;
        const int wn = (wave & 3) * 32;

        const bf16* gA = a.W3bf + (size_t)(bm + srow) * NN + scol;
        const bf16* gB = a.W3t  + (size_t)(bn + srow) * NN + scol;

        f32x4 acc[4][2];
#pragma unroll
        for (int i = 0; i < 4; ++i)
#pragma unroll
            for (int j = 0; j < 2; ++j) acc[i][j] = (f32x4){0.f, 0.f, 0.f, 0.f};

        auto issue = [&](int buf, int kt) {
            const int kof = kt * BK;
            async_copy16(&LA[buf][off0], gA + kof);
            async_copy16(&LB[buf][off0], gB + kof);
        };

        issue(0, 0); issue(1, 1); issue(2, 2);   // 6 outstanding
        WAIT_VM(4); BAR();

#pragma unroll 1
        for (int kt = 0; kt < NK; ++kt) {
            const int b = kt & 3;
            const bf16* cA = LA[b];
            const bf16* cB = LB[b];

            bf16x8 af[4], f1[2];
#pragma unroll
            for (int i = 0; i < 4; ++i)
                af[i] = *(const bf16x8*)&cA[(wm + i * 16 + lrow) * BK + qe];
#pragma unroll
            for (int j = 0; j < 2; ++j)
                f1[j] = *(const bf16x8*)&cB[(wn + j * 16 + lrow) * BK + qe];
            if (kt < NK - 3) issue((kt + 3) & 3, kt + 3);

            BAR(); LGKM0();
            __builtin_amdgcn_s_setprio(1);
#pragma unroll
            for (int i = 0; i < 4; ++i)
#pragma unroll
                for (int j = 0; j < 2; ++j)
                    acc[i][j] = __builtin_amdgcn_mfma_f32_16x16x32_bf16(
                        af[i], f1[j], acc[i][j], 0, 0, 0);
            __builtin_amdgcn_s_setprio(0);
            if (kt < NK - 3)       { WAIT_VM(4); }
            else if (kt == NK - 3) { WAIT_VM(2); }
            else                   { WAIT_VM(0); }
            BAR();
        }

#pragma unroll
        for (int i = 0; i < 4; ++i)
#pragma unroll
            for (int j = 0; j < 2; ++j)
#pragma unroll
                for (int r = 0; r < 4; ++r)
                    a.M3[(size_t)(bm + wm + i * 16 + q * 4 + r) * NN +
                         (bn + wn + j * 16 + lrow)] = acc[i][j][r];
    }
}

// ---------------------------------------------------------------------------
// Phase 2: dual-A GEMM (m5 = M1bf@A, m4 = B1bf@A, shared B = At rows) with
// the same phased core, 128x128 tile, wave grid 4x2 (max shared-B reuse),
// fused final epilogue: out = M1*M2 + M1 + M3 + M3*(m4*W1)*(M3 + m5).
// ---------------------------------------------------------------------------
struct Gemm2Args {
    const bf16*  M1bf;
    const bf16*  B1bf;
    const bf16*  At;
    const float* M1;
    const float* M3;
    const float* W1;
    float*       out;
};

__global__ __launch_bounds__(512, 2) void gemm2_fused_kernel(Gemm2Args a) {
    __shared__ __align__(16) bf16 L5[4][128 * BK];
    __shared__ __align__(16) bf16 L4[4][128 * BK];
    __shared__ __align__(16) bf16 LBt[4][128 * BK];

    const int t = threadIdx.x;
    const int wg  = blockIdx.y * 16 + blockIdx.x;
    const int swz = (wg & 7) * 32 + (wg >> 3);
    const int bm  = (swz >> 4) * 128;
    const int bn  = (swz & 15) * 128;

    const int srow = t >> 2;
    const int sch  = t & 3;
    const int scol = ((sch ^ ((srow >> 1) & 3)) << 3);
    const int off0 = t * 8;

    const int wave = t >> 6;
    const int lane = t & 63;
    const int wm   = (wave >> 1) * 32;   // 4 waves along M
    const int wn   = (wave & 1) * 64;    // 2 waves along N
    const int lrow = lane & 15;
    const int q    = lane >> 4;
    const int qe   = (q ^ ((lrow >> 1) & 3)) << 3;

    const bf16* g5 = a.M1bf + (size_t)(bm + srow) * NN + scol;
    const bf16* g4 = a.B1bf + (size_t)(bm + srow) * NN + scol;
    const bf16* gB = a.At   + (size_t)(bn + srow) * NN + scol;

    f32x4 acc5[2][4], acc4[2][4];
#pragma unroll
    for (int i = 0; i < 2; ++i)
#pragma unroll
        for (int j = 0; j < 4; ++j) {
            acc5[i][j] = (f32x4){0.f, 0.f, 0.f, 0.f};
            acc4[i][j] = (f32x4){0.f, 0.f, 0.f, 0.f};
        }

    auto issue = [&](int buf, int kt) {
        const int kof = kt * BK;
        async_copy16(&L5[buf][off0],  g5 + kof);
        async_copy16(&L4[buf][off0],  g4 + kof);
        async_copy16(&LBt[buf][off0], gB + kof);
    };

    issue(0, 0); issue(1, 1); issue(2, 2);
    WAIT_VM(6); BAR();

#pragma unroll 1
    for (int kt = 0; kt < NK; ++kt) {
        const int b = kt & 3;
        const bf16* c5 = L5[b];
        const bf16* c4 = L4[b];
        const bf16* cB = LBt[b];

        bf16x8 a5[2], a4[2], bfr[4];
#pragma unroll
        for (int i = 0; i < 2; ++i) {
            a5[i] = *(const bf16x8*)&c5[(wm + i * 16 + lrow) * BK + qe];
            a4[i] = *(const bf16x8*)&c4[(wm + i * 16 + lrow) * BK + qe];
        }
#pragma unroll
        for (int j = 0; j < 4; ++j)
            bfr[j] = *(const bf16x8*)&cB[(wn + j * 16 + lrow) * BK + qe];
        if (kt < NK - 3) issue((kt + 3) & 3, kt + 3);

        BAR(); LGKM0();
        __builtin_amdgcn_s_setprio(1);
#pragma unroll
        for (int i = 0; i < 2; ++i)
#pragma unroll
            for (int j = 0; j < 4; ++j) {
                acc5[i][j] = __builtin_amdgcn_mfma_f32_16x16x32_bf16(
                    a5[i], bfr[j], acc5[i][j], 0, 0, 0);
                acc4[i][j] = __builtin_amdgcn_mfma_f32_16x16x32_bf16(
                    a4[i], bfr[j], acc4[i][j], 0, 0, 0);
            }
        __builtin_amdgcn_s_setprio(0);
        if (kt < NK - 3)       { WAIT_VM(6); }
        else if (kt == NK - 3) { WAIT_VM(3); }
        else                   { WAIT_VM(0); }
        BAR();
    }

    // fused final epilogue: out = M1*M2 + M1 + M3 + M3*(m4*W1)*(M3 + m5)
#pragma unroll
    for (int i = 0; i < 2; ++i)
#pragma unroll
        for (int j = 0; j < 4; ++j)
#pragma unroll
            for (int r = 0; r < 4; ++r) {
                const size_t idx = (size_t)(bm + wm + i * 16 + q * 4 + r) * NN +
                                   (bn + wn + j * 16 + lrow);
                const float m5 = acc5[i][j][r];
                const float m4 = acc4[i][j][r];
                const float m1 = a.M1[idx];
                const float m3 = a.M3[idx];
                const float w1 = a.W1[idx];
                const float m2 = a.out[idx];
                a.out[idx] = m1 * m2 + m1 + m3 + m3 * (m4 * w1) * (m3 + m5);
            }
}

// ---------------------------------------------------------------------------
extern "C" void kernel_launch(void* const* d_in, const int* in_sizes, int n_in,
                              void* d_out, int out_size, void* d_ws, size_t ws_size,
                              hipStream_t stream) {
    const float* A  = (const float*)d_in[0];
    const float* W1 = (const float*)d_in[1];
    const float* W2 = (const float*)d_in[2];
    const float* W3 = (const float*)d_in[3];
    float* out = (float*)d_out;

    const size_t P = (size_t)NN * NN;
    char* ws = (char*)d_ws;

    bf16* Abf  = (bf16*)ws;            // P*2 bytes each
    bf16* At   = Abf + P;
    bf16* W1t  = At + P;
    bf16* W2t  = W1t + P;
    bf16* W3bf = W2t + P;
    bf16* W3t  = W3bf + P;
    bf16* M1bf = W3t + P;
    bf16* B1bf = M1bf + P;
    float* M1  = (float*)(B1bf + P);   // P*4 bytes each
    float* M3  = M1 + P;
    // total: 8*2*P + 2*4*P = 24*P = 96 MiB

    CastArgs ca;
    ca.in[0] = A;  ca.outT[0] = At;  ca.outN[0] = Abf;
    ca.in[1] = W1; ca.outT[1] = W1t; ca.outN[1] = nullptr;
    ca.in[2] = W2; ca.outT[2] = W2t; ca.outN[2] = nullptr;
    ca.in[3] = W3; ca.outT[3] = W3t; ca.outN[3] = W3bf;
    transpose_cast_kernel<<<dim3(NN / 64, NN / 64, 4), 256, 0, stream>>>(ca);

    // z=0: dual (M1 = A@W1, M2 = A@W2, + M1bf/B1bf);  z=1: M3 = W3@W3
    P1Args p1;
    p1.Abf = Abf; p1.W1t = W1t; p1.W2t = W2t; p1.W3bf = W3bf; p1.W3t = W3t;
    p1.M1 = M1; p1.M2out = out; p1.M3 = M3;
    p1.W1 = W1; p1.M1bf = M1bf; p1.B1bf = B1bf;
    gemm_dual_kernel<<<dim3(NN / 128, NN / 128, 2), 512, 0, stream>>>(p1);

    // dual-A GEMM (m5 = M1bf@A, m4 = B1bf@A) + fused final epilogue
    Gemm2Args g2;
    g2.M1bf = M1bf; g2.B1bf = B1bf; g2.At = At;
    g2.M1 = M1; g2.M3 = M3; g2.W1 = W1; g2.out = out;
    gemm2_fused_kernel<<<dim3(NN / 128, NN / 128), 512, 0, stream>>>(g2);
}